// Round 1
// baseline (144.955 us; speedup 1.0000x reference)
//
#include <hip/hip_runtime.h>
#include <stdint.h>

// out = conv3x3_zeropad(s, W_eff), s = 3x3 reflect-pad box sum of x (B=16,C=64,H=W=128)
// R6: boxsumT with XOR-swizzled transpose buffer (16-way -> 4-way write conflict,
// CF reads), single barrier/row via tb double-buffer, weff folded into the same
// launch (block 256). conv_kernel unchanged from R4/R5 (verified).

#define THETA 0.7f

typedef __attribute__((ext_vector_type(8))) short bf16x8;
typedef __attribute__((ext_vector_type(16))) float f32x16;

__device__ inline unsigned short f2bf(float f) {
    unsigned u = __float_as_uint(f);
    u = (u + 0x7FFFu + ((u >> 16) & 1u)) >> 16;   // RNE
    return (unsigned short)u;
}
__device__ inline void async16(const void* g, void* l) {
    __builtin_amdgcn_global_load_lds(
        (const __attribute__((address_space(1))) unsigned int*)g,
        (__attribute__((address_space(3))) unsigned int*)l, 16, 0, 0);
}

// ---------------------------------------------------------------------------
// Kernel 1: blocks 0..255 = fused box-sum + transpose (x fp32 NCHW -> s bf16
// NHWC); block 256 = W_eff -> Wt2 bf16 lane-contiguous MFMA-A layout.
//
// boxsumT: w4 = tid&31 (float4 along w), cg = tid>>5 (4 channels each).
// Rolling vertical float4 sums; horizontal via shfl within 32-lane w-groups
// (reflect at edges). Transpose buffer tb[2][128 W][8 units of 16B], physical
// unit p = u ^ ((W>>2)&7):
//   write ushort4 (u = cg>>1, half = cg&1): bank = 4*(u^(w4&7)) + 2h
//     -> 8 groups x 4 lanes = 4-way (was 16-way at stride-72)
//   flush bf16x8 read at p = c8 ^ ((w>>2)&7): minimum-aliasing, conflict-free
// Single __syncthreads per row (buffers alternate r&1).
//
// weff: Wt2[(((tap*4+ic)*2+mf)*64 + lane)*8 + j] = W_eff[o][ch][tap]
//   o = mf*32 + (lane&31), ch = ic*16 + (lane>>5)*8 + j
// ---------------------------------------------------------------------------
__global__ __launch_bounds__(512) void boxweff_kernel(const float* __restrict__ x,
                                                      const float* __restrict__ W,
                                                      unsigned short* __restrict__ Wt2,
                                                      unsigned short* __restrict__ s) {
    int bid = blockIdx.x;
    int tid = threadIdx.x;

    if (bid >= 256) {
        // ---- weff path: 512 threads, one block ----
        int t = tid;
        int o = t >> 3;
        int ch8 = t & 7;
        int c0 = ch8 * 8;
        int ic = ch8 >> 1;
        int mf = o >> 5;
        int lane = (o & 31) | ((ch8 & 1) << 5);

        float v[8][9];
        float tsum[8];
#pragma unroll
        for (int j = 0; j < 8; j++) {
            const float* w = W + ((size_t)o * 64 + c0 + j) * 9;
            float sum = 0.f;
#pragma unroll
            for (int k = 0; k < 9; k++) { v[j][k] = w[k]; sum += v[j][k]; }
            tsum[j] = sum;
        }
#pragma unroll
        for (int tap = 0; tap < 9; tap++) {
            unsigned short* dst = Wt2 + (((size_t)(tap * 4 + ic) * 2 + mf) * 64 + lane) * 8;
#pragma unroll
            for (int j = 0; j < 8; j++) {
                float val = v[j][tap] - ((tap == 4) ? THETA * tsum[j] : 0.f);
                dst[j] = f2bf(val);
            }
        }
        return;
    }

    // ---- boxsumT path ----
    __shared__ unsigned short tb[2][128 * 64];   // 2 x 16 KiB
    int b = bid >> 4;
    int h0 = (bid & 15) * 8;
    int w4 = tid & 31;
    int cg = tid >> 5;          // 0..15, 4 channels each
    int c0 = cg * 4;
    int u8 = cg >> 1;           // 16B unit index (8 channels)
    int hh = (cg & 1) * 4;      // half-unit offset in shorts
    int sw = w4 & 7;            // XOR swizzle key (= (W>>2)&7 for W = 4*w4+k)
    const float* xp = x + ((size_t)(b * 64 + c0)) * 16384 + w4 * 4;

    float4 A[4], B[4], C[4];
    int hm = (h0 == 0) ? 1 : h0 - 1;
#pragma unroll
    for (int cc = 0; cc < 4; cc++) {
        A[cc] = *(const float4*)(xp + (size_t)cc * 16384 + hm * 128);
        B[cc] = *(const float4*)(xp + (size_t)cc * 16384 + h0 * 128);
        C[cc] = *(const float4*)(xp + (size_t)cc * 16384 + (h0 + 1) * 128);
    }

#pragma unroll
    for (int r = 0; r < 8; r++) {
        unsigned short* tbr = tb[r & 1];

        // prefetch next C (issued before compute so latency overlaps)
        float4 Cn[4];
        if (r < 7) {
            int hn = h0 + 2 + r;
            if (hn > 127) hn = 126;
#pragma unroll
            for (int cc = 0; cc < 4; cc++)
                Cn[cc] = *(const float4*)(xp + (size_t)cc * 16384 + hn * 128);
        }

        unsigned short res[4][4];   // [cc][k]
#pragma unroll
        for (int cc = 0; cc < 4; cc++) {
            float4 vs;
            vs.x = A[cc].x + B[cc].x + C[cc].x;
            vs.y = A[cc].y + B[cc].y + C[cc].y;
            vs.z = A[cc].z + B[cc].z + C[cc].z;
            vs.w = A[cc].w + B[cc].w + C[cc].w;
            float L = __shfl_up(vs.w, 1, 32);
            float R = __shfl_down(vs.x, 1, 32);
            float sx = (w4 == 0) ? vs.x + 2.f * vs.y : L + vs.x + vs.y;
            float sy = vs.x + vs.y + vs.z;
            float sz = vs.y + vs.z + vs.w;
            float sw_ = (w4 == 31) ? 2.f * vs.z + vs.w : vs.z + vs.w + R;
            res[cc][0] = f2bf(sx);
            res[cc][1] = f2bf(sy);
            res[cc][2] = f2bf(sz);
            res[cc][3] = f2bf(sw_);
        }
        // write transpose buffer: W = w4*4+k rows of 8 swizzled 16B units
#pragma unroll
        for (int k = 0; k < 4; k++) {
            ushort4 o4 = make_ushort4(res[0][k], res[1][k], res[2][k], res[3][k]);
            *(ushort4*)(tbr + (size_t)(w4 * 4 + k) * 64 + ((u8 ^ sw) << 3) + hh) = o4;
        }
#pragma unroll
        for (int cc = 0; cc < 4; cc++) { A[cc] = B[cc]; B[cc] = C[cc]; C[cc] = Cn[cc]; }
        __syncthreads();

        // flush row h0+r: 1024 chunks of 16 B, full-line NHWC stores.
        // No trailing barrier: next row writes the other tb buffer.
        unsigned short* sp = s + (((size_t)b * 128 + (h0 + r)) * 128) * 64;
#pragma unroll
        for (int f = 0; f < 2; f++) {
            int id = f * 512 + tid;
            int w = id >> 3, c8 = id & 7;
            int p = c8 ^ ((w >> 2) & 7);
            bf16x8 v = *(const bf16x8*)(tbr + (size_t)w * 64 + p * 8);
            *(bf16x8*)(sp + (size_t)w * 64 + c8 * 8) = v;
        }
    }
}

// ---------------------------------------------------------------------------
// Kernel 2: implicit-GEMM conv, mfma_f32_32x32x16_bf16. UNCHANGED (verified).
// Block = (b, 4 h-rows, 64-px w-tile), 4 waves; wave = 1 row x 64 px x 64 o
// (mf=2 x nf=2, acc[2][2] of f32x16). LDS staging: 6 rows x 66 slots x 64c
// bf16, 16B chunks XOR-swizzled g = u ^ (slot&7). A from global Wt2
// (lane-contiguous), tap-major prefetch. Grid 1024.
// ---------------------------------------------------------------------------
__global__ __launch_bounds__(256, 2) void conv_kernel(const unsigned short* __restrict__ s,
                                                      const unsigned short* __restrict__ Wt2,
                                                      float* __restrict__ out) {
    __shared__ __align__(16) unsigned short sS[6 * 66 * 64];   // 50688 B

    int bid = blockIdx.x;
    int b = bid >> 6;
    int h0 = ((bid >> 1) & 31) * 4;
    int w0 = (bid & 1) * 64;
    int tid = threadIdx.x;
    int lane = tid & 63;
    int wv = tid >> 6;
    int n32 = lane & 31;
    int q2 = lane >> 5;

    const char* sb = (const char*)s + ((size_t)b * 128) * 16384;

    int4 z = make_int4(0, 0, 0, 0);
    if (h0 == 0)
        for (int i = tid; i < 528; i += 256) *(int4*)((char*)sS + (size_t)i * 16) = z;
    if (h0 == 124)
        for (int i = tid; i < 528; i += 256) *(int4*)((char*)sS + (size_t)(5 * 528 + i) * 16) = z;

    // halo slots 0 and 65 (plain loads; per-lane divergence safe here)
    if (tid < 96) {
        int r = tid >> 4;
        int side = (tid >> 3) & 1;
        int g = tid & 7;
        int slot = side ? 65 : 0;
        int hg = h0 - 1 + r;
        int wg = w0 - 1 + slot;
        int4 v = z;
        if ((unsigned)hg < 128u && (unsigned)wg < 128u) {
            int u = g ^ (slot & 7);
            v = *(const int4*)(sb + (size_t)hg * 16384 + (size_t)wg * 128 + u * 16);
        }
        *(int4*)((char*)sS + (size_t)(r * 528 + slot * 8 + g) * 16) = v;
    }

    // interior: full-wave async, iteration-uniform row predicate
#pragma unroll
    for (int it = 0; it < 12; it++) {
        int row = it >> 1;
        int hg = h0 - 1 + row;
        if (hg < 0 || hg > 127) continue;
        int rem = (it & 1) * 256 + tid;
        int slot = 1 + (rem >> 3);
        int g = rem & 7;
        int wg = w0 + (rem >> 3);
        int u = g ^ (slot & 7);
        async16(sb + (size_t)hg * 16384 + (size_t)wg * 128 + u * 16,
                (char*)sS + (size_t)(row * 528 + 8 + rem) * 16);
    }
    __syncthreads();

    // B LDS offsets (shorts) per (kx, ic); add (wv+ky)*4224 + nf*2048
    int p0[3][4];
#pragma unroll
    for (int kx = 0; kx < 3; kx++)
#pragma unroll
        for (int ic = 0; ic < 4; ic++) {
            int slot = n32 + kx;
            int g = (ic * 2 + q2) ^ (slot & 7);
            p0[kx][ic] = slot * 64 + g * 8;
        }

    f32x16 acc[2][2];
#pragma unroll
    for (int mf = 0; mf < 2; mf++)
#pragma unroll
        for (int nf = 0; nf < 2; nf++)
#pragma unroll
            for (int r = 0; r < 16; r++) acc[mf][nf][r] = 0.f;

    // A-frags for tap 0
    bf16x8 Af[8], An[8];
#pragma unroll
    for (int ic = 0; ic < 4; ic++)
#pragma unroll
        for (int mf = 0; mf < 2; mf++)
            Af[ic * 2 + mf] = *(const bf16x8*)(Wt2 + (((size_t)(0 * 4 + ic) * 2 + mf) * 64 + lane) * 8);

#pragma unroll
    for (int tap = 0; tap < 9; tap++) {
        int ky = tap / 3, kx = tap % 3;
        if (tap < 8) {
#pragma unroll
            for (int ic = 0; ic < 4; ic++)
#pragma unroll
                for (int mf = 0; mf < 2; mf++)
                    An[ic * 2 + mf] = *(const bf16x8*)(Wt2 + (((size_t)((tap + 1) * 4 + ic) * 2 + mf) * 64 + lane) * 8);
        }
#pragma unroll
        for (int ic = 0; ic < 4; ic++) {
            const unsigned short* bp = sS + (size_t)(wv + ky) * 4224 + p0[kx][ic];
            bf16x8 b0 = *(const bf16x8*)(bp);
            bf16x8 b1 = *(const bf16x8*)(bp + 2048);
            acc[0][0] = __builtin_amdgcn_mfma_f32_32x32x16_bf16(Af[ic * 2 + 0], b0, acc[0][0], 0, 0, 0);
            acc[0][1] = __builtin_amdgcn_mfma_f32_32x32x16_bf16(Af[ic * 2 + 0], b1, acc[0][1], 0, 0, 0);
            acc[1][0] = __builtin_amdgcn_mfma_f32_32x32x16_bf16(Af[ic * 2 + 1], b0, acc[1][0], 0, 0, 0);
            acc[1][1] = __builtin_amdgcn_mfma_f32_32x32x16_bf16(Af[ic * 2 + 1], b1, acc[1][1], 0, 0, 0);
        }
        if (tap < 8) {
#pragma unroll
            for (int k = 0; k < 8; k++) Af[k] = An[k];
        }
    }

    // epilogue: 32x32 C/D layout col=lane&31 (pixel), row=(r&3)+8*(r>>2)+4*q2 (o)
    float* ob = out + ((size_t)b * 64) * 16384 + (size_t)(h0 + wv) * 128 + w0;
#pragma unroll
    for (int mf = 0; mf < 2; mf++)
#pragma unroll
        for (int nf = 0; nf < 2; nf++)
#pragma unroll
            for (int r = 0; r < 16; r++) {
                int o = mf * 32 + (r & 3) + 8 * (r >> 2) + 4 * q2;
                ob[(size_t)o * 16384 + nf * 32 + n32] = acc[mf][nf][r];
            }
}

// ---------------------------------------------------------------------------
extern "C" void kernel_launch(void* const* d_in, const int* in_sizes, int n_in,
                              void* d_out, int out_size, void* d_ws, size_t ws_size,
                              hipStream_t stream) {
    const float* x = (const float*)d_in[0];   // [16][64][128][128] fp32
    const float* W = (const float*)d_in[1];   // [64][64][3][3] fp32
    float* outp = (float*)d_out;

    // ws: Wt2 bf16 (73728 B) | s bf16 NHWC (33554432 B)
    unsigned short* Wt2 = (unsigned short*)d_ws;
    unsigned short* s = (unsigned short*)((char*)d_ws + 73728);

    boxweff_kernel<<<257, 512, 0, stream>>>(x, W, Wt2, s);
    conv_kernel<<<1024, 256, 0, stream>>>(s, Wt2, outp);
}